// Round 12
// baseline (43.467 us; speedup 1.0000x reference)
//
#include <hip/hip_runtime.h>
#include <math.h>

#define NB 4
#define WDIM 128
#define KDIM 256
#define EDIM 256

__device__ __forceinline__ float dot4(float4 a, float4 b) {
    return a.x * b.x + a.y * b.y + a.z * b.z + a.w * b.w;
}
__device__ __forceinline__ void nt_store(float v, float* p) {
    __builtin_nontemporal_store(v, p);
}

// ---------------- k_ut12: dual GEMM u,t (r6-verified body, nt stores) ----------------
// grid 512: blk = b*128 + kt*4 + eq. Block = 8 k x 64 e.
__global__ __launch_bounds__(256) void k_ut12(const float* __restrict__ x,
                                              const float* __restrict__ lin_w,
                                              const float* __restrict__ lin_b,
                                              float* __restrict__ u_ws,
                                              float* __restrict__ t_ws) {
    __shared__ float vrow[8 * WDIM];   // [k 8][w 128]
    const int blk = blockIdx.x;
    const int b  = blk >> 7;
    const int kt = (blk >> 2) & 31;
    const int eq = blk & 3;
    const int k0 = kt * 8;
    const int tid = threadIdx.x;
    const int e   = eq * 64 + (tid & 63);
    const int ks  = tid >> 6;

    if (tid < WDIM) {
        const float* xp = x + ((size_t)b * WDIM + tid) * KDIM + k0;
        float4 v0 = *(const float4*)xp;
        float4 v1 = *(const float4*)(xp + 4);
        vrow[0 * WDIM + tid] = v0.x; vrow[1 * WDIM + tid] = v0.y;
        vrow[2 * WDIM + tid] = v0.z; vrow[3 * WDIM + tid] = v0.w;
        vrow[4 * WDIM + tid] = v1.x; vrow[5 * WDIM + tid] = v1.y;
        vrow[6 * WDIM + tid] = v1.z; vrow[7 * WDIM + tid] = v1.w;
    }
    __syncthreads();

    const float4* wr = (const float4*)(lin_w + (size_t)e * 2 * WDIM);
    float u0 = 0.f, u1 = 0.f, t0 = 0.f, t1 = 0.f;
#pragma unroll 8
    for (int q = 0; q < 32; ++q) {
        float4 w1 = wr[q];
        float4 w2 = wr[32 + q];
        float4 va = *(const float4*)&vrow[(ks * 2 + 0) * WDIM + q * 4];
        float4 vb = *(const float4*)&vrow[(ks * 2 + 1) * WDIM + q * 4];
        u0 += dot4(w1, va); u1 += dot4(w1, vb);
        t0 += dot4(w2, va); t1 += dot4(w2, vb);
    }
    const float lb = lin_b[e];
    const int k = k0 + ks * 2;
    const size_t o0 = ((size_t)b * KDIM + k) * EDIM + e;
    nt_store(u0,      u_ws + o0);
    nt_store(u1,      u_ws + o0 + EDIM);
    nt_store(t0 + lb, t_ws + o0);
    nt_store(t1 + lb, t_ws + o0 + EDIM);
}

// ---------------- k_e12: e[b,i,j] = 0.4*sum a|u+t| + 0.6*(ru+rt) + bias ----------------
// grid 1024: blk = b*256 + it*8 + jt. Block = 8i x 32j; wave owns 8 disjoint j's.
// lane = (s = lane&7 e-slice, jj = lane>>3). ZERO LDS. (r11-verified body, nt e-stores)
__global__ __launch_bounds__(256) void k_e12(const float* __restrict__ a_vec,
                                             const float* __restrict__ bias,
                                             const float* __restrict__ u_ws,
                                             const float* __restrict__ t_ws,
                                             float* __restrict__ e_ws) {
    const int blk = blockIdx.x;
    const int b   = blk >> 8;
    const int wid = blk & 255;
    const int i0  = (wid >> 3) * 8;
    const int jt  = wid & 7;
    const int tid  = threadIdx.x;
    const int wv   = tid >> 6;
    const int lane = tid & 63;
    const int s  = lane & 7;
    const int jj = lane >> 3;
    const int j  = jt * 32 + wv * 8 + jj;

    // t row slice in regs (8 lanes cover 128B of each of 8 rows per load)
    const float* trp = t_ws + ((size_t)b * KDIM + j) * EDIM;
    float4 tld[8];
#pragma unroll
    for (int q = 0; q < 8; ++q) tld[q] = *(const float4*)(trp + q * 32 + s * 4);

    float4 av[8];
#pragma unroll
    for (int q = 0; q < 8; ++q) av[q] = *(const float4*)(a_vec + q * 32 + s * 4);

    // rt = sum a*t, reduced over s now (all lanes end with full rt)
    float rt = 0.f;
#pragma unroll
    for (int q = 0; q < 8; ++q) rt += dot4(av[q], tld[q]);
    rt += __shfl_xor(rt, 1, 64);
    rt += __shfl_xor(rt, 2, 64);
    rt += __shfl_xor(rt, 4, 64);

#pragma unroll
    for (int p = 0; p < 2; ++p) {
        const int ib = i0 + p * 4;
        const float* up0 = u_ws + ((size_t)b * KDIM + ib) * EDIM;
        float acc[4] = {0.f, 0.f, 0.f, 0.f};
        float ru[4]  = {0.f, 0.f, 0.f, 0.f};
#pragma unroll
        for (int q = 0; q < 8; ++q) {
            const float4 aa = av[q];
            const float4 t4 = tld[q];
#pragma unroll
            for (int i = 0; i < 4; ++i) {
                float4 u4 = *(const float4*)(up0 + (size_t)i * EDIM + q * 32 + s * 4);
                ru[i]  += dot4(aa, u4);
                acc[i] += aa.x * fabsf(u4.x + t4.x) + aa.y * fabsf(u4.y + t4.y)
                        + aa.z * fabsf(u4.z + t4.z) + aa.w * fabsf(u4.w + t4.w);
            }
        }
#pragma unroll
        for (int i = 0; i < 4; ++i) {
            float z = 0.4f * acc[i] + 0.6f * ru[i];
            z += __shfl_xor(z, 1, 64);
            z += __shfl_xor(z, 2, 64);
            z += __shfl_xor(z, 4, 64);
            z += 0.6f * rt;
            if (s == 0) {
                nt_store(z + bias[(size_t)(ib + i) * KDIM + j],
                         e_ws + ((size_t)b * KDIM + ib + i) * KDIM + j);
            }
        }
    }
}

// ---------------- k_sh12: softmax + h = sigmoid(attn @ v), transposed write ----------------
// grid 1024: blk = b*256 + it*4 + wq. Block = 4 i's x 32 w's. (r11-verified body)
__global__ __launch_bounds__(256) void k_sh12(const float* __restrict__ x,
                                              const float* __restrict__ e_ws,
                                              float* __restrict__ out) {
    __shared__ float attn_lds[4][260];
    const int blk = blockIdx.x;
    const int b   = blk >> 8;
    const int wid = blk & 255;
    const int i0  = (wid >> 2) * 4;
    const int w0  = (wid & 3) * 32;
    const int tid  = threadIdx.x;
    const int wv   = tid >> 6;
    const int lane = tid & 63;

    // softmax of row i0+wv (wave-parallel, contiguous 1 KB read)
    {
        float4 ev = *(const float4*)(e_ws + ((size_t)b * KDIM + i0 + wv) * KDIM + lane * 4);
        float m = fmaxf(fmaxf(ev.x, ev.y), fmaxf(ev.z, ev.w));
#pragma unroll
        for (int o = 1; o < 64; o <<= 1) m = fmaxf(m, __shfl_xor(m, o, 64));
        float4 p;
        p.x = __expf(ev.x - m); p.y = __expf(ev.y - m);
        p.z = __expf(ev.z - m); p.w = __expf(ev.w - m);
        float ssum = p.x + p.y + p.z + p.w;
#pragma unroll
        for (int o = 1; o < 64; o <<= 1) ssum += __shfl_xor(ssum, o, 64);
        const float inv = 1.0f / ssum;
        p.x *= inv; p.y *= inv; p.z *= inv; p.w *= inv;
        *(float4*)&attn_lds[wv][lane * 4] = p;
    }
    __syncthreads();

    // h-phase: wave wv -> w-oct; lane: s = lane&7 (j-slices), ww = lane>>3
    const int s  = lane & 7;
    const int ww = lane >> 3;
    const int w  = w0 + wv * 8 + ww;
    const float* xr = x + ((size_t)b * WDIM + w) * KDIM;
    float acc[4] = {0.f, 0.f, 0.f, 0.f};
#pragma unroll
    for (int q = 0; q < 8; ++q) {
        float4 x4 = *(const float4*)(xr + q * 32 + s * 4);
#pragma unroll
        for (int i = 0; i < 4; ++i) {
            float4 at = *(const float4*)&attn_lds[i][q * 32 + s * 4];
            acc[i] += dot4(at, x4);
        }
    }
#pragma unroll
    for (int i = 0; i < 4; ++i) {
        acc[i] += __shfl_xor(acc[i], 1, 64);
        acc[i] += __shfl_xor(acc[i], 2, 64);
        acc[i] += __shfl_xor(acc[i], 4, 64);
    }
    if (s == 0) {
        float4 o;
        o.x = 1.f / (1.f + __expf(-acc[0]));
        o.y = 1.f / (1.f + __expf(-acc[1]));
        o.z = 1.f / (1.f + __expf(-acc[2]));
        o.w = 1.f / (1.f + __expf(-acc[3]));
        *(float4*)(out + ((size_t)b * WDIM + w) * KDIM + i0) = o;
    }
}

extern "C" void kernel_launch(void* const* d_in, const int* in_sizes, int n_in,
                              void* d_out, int out_size, void* d_ws, size_t ws_size,
                              hipStream_t stream) {
    (void)in_sizes; (void)n_in; (void)out_size; (void)ws_size;
    const float* x     = (const float*)d_in[0];
    const float* lin_w = (const float*)d_in[1];
    const float* lin_b = (const float*)d_in[2];
    const float* a_vec = (const float*)d_in[3];
    const float* bias  = (const float*)d_in[4];
    float* out = (float*)d_out;

    float* u_ws = (float*)d_ws;                      // 262144 f
    float* t_ws = u_ws + (size_t)NB * KDIM * EDIM;   // 262144 f
    float* e_ws = t_ws + (size_t)NB * KDIM * EDIM;   // 262144 f

    k_ut12<<<512, 256, 0, stream>>>(x, lin_w, lin_b, u_ws, t_ws);
    k_e12<<<1024, 256, 0, stream>>>(a_vec, bias, u_ws, t_ws, e_ws);
    k_sh12<<<1024, 256, 0, stream>>>(x, e_ws, out);
}